// Round 8
// baseline (200.415 us; speedup 1.0000x reference)
//
#include <hip/hip_runtime.h>
#include <hip/hip_bf16.h>
#include <math.h>

#define H 128
#define W 128
#define C 128
#define BATCH 2
#define NPIX (H*W)            // 16384
#define CSPLIT 4
#define PART_ELEMS (CSPLIT*BATCH*27*NPIX)   // 3538944 floats
#define PX 32                 // pixels per dcn block

// ws layout (bytes): part 14155776 | wPack 294912 | xT 16777216  = 31.2 MB
#define WS_WPK_OFF 14155776
#define WS_XT_OFF  14450688

typedef __attribute__((ext_vector_type(8))) short bf16x8;
typedef __attribute__((ext_vector_type(4))) float f32x4;

static __device__ __forceinline__ unsigned short f2bf(float f){
  unsigned u = __float_as_uint(f);
  u += 0x7FFF + ((u >> 16) & 1);          // RNE
  return (unsigned short)(u >> 16);
}

// ---------------------------------------------------------------------------
// Kernel 1: offset(18)+modulation(9) 3x3 conv + NHWC transpose of x.
// Grid 512 = 4 s-splits x 2 batch x 64 tiles (8 rows x 32 cols) = 2 blocks/CU.
// Thread = (csub: 8ch, 4 px). 4 px/thread doubles FMA per weight s_load dword
// vs round 7. c8 loop kept rolled (I$). Reduce stride 29 (odd) -> conflict-free
// (round-7 stride 56 was a 16-way bank conflict).
// ---------------------------------------------------------------------------
__global__ __launch_bounds__(256) void conv27_kernel(
    const float* __restrict__ x, const float* __restrict__ w_p,
    const float* __restrict__ w_m, float* __restrict__ part,
    float* __restrict__ xT)
{
  __shared__ float smem[14848];  // halo 32ch x 10 x 34 = 10880; red 2*4*64*29 = 14848

  int bid  = blockIdx.x;
  int s    = bid & 3;
  int b    = (bid >> 2) & 1;
  int tile = bid >> 3;               // 0..63
  int i0   = (tile >> 2) << 3;       // 16 row-tiles * 8
  int j0   = (tile & 3) << 5;        // 4 col-tiles * 32
  int tid  = threadIdx.x;
  int csub = __builtin_amdgcn_readfirstlane(tid >> 6);
  int pl   = tid & 63;
  int li   = pl >> 4, lj = pl & 15;  // rows 0..3 (+4), cols 0..15 (+16)

  // ---- stage halo: 32 ch x 10 x 34 ----
  const float* xb = x + ((long)b*C + s*32)*NPIX;
  for (int t = 0; t < 43; ++t) {
    int e = t*256 + tid;
    if (e < 10880) {
      int ch = e/340; int rem = e - ch*340;
      int r  = rem/34; int cc = rem - r*34;
      int gi = i0 - 1 + r, gj = j0 - 1 + cc;
      float v = 0.f;
      if (gi >= 0 && gi < H && gj >= 0 && gj < W)
        v = xb[(long)ch*NPIX + gi*W + gj];
      smem[ch*340 + r*34 + cc] = v;
    }
  }
  __syncthreads();

  // ---- emit xT (NHWC fp32): 4 px x 8 ch per thread ----
  {
    int cbase = s*32 + csub*8;
#pragma unroll
    for (int ph = 0; ph < 2; ++ph)
#pragma unroll
      for (int jh = 0; jh < 2; ++jh) {
        int row = li + ph*4, col = lj + jh*16;
        int p   = (i0+row)*W + (j0+col);
        const float* sp = &smem[(csub*8)*340 + (row+1)*34 + (col+1)];
        float4 v0 = make_float4(sp[0],    sp[340],  sp[680],  sp[1020]);
        float4 v1 = make_float4(sp[1360], sp[1700], sp[2040], sp[2380]);
        float* dst = xT + ((long)b*NPIX + p)*C + cbase;
        *(float4*)dst = v0; *(float4*)(dst+4) = v1;
      }
  }

  float acc[2][2][27];
#pragma unroll
  for (int ph = 0; ph < 2; ++ph)
#pragma unroll
    for (int jh = 0; jh < 2; ++jh)
#pragma unroll
      for (int o = 0; o < 27; ++o) acc[ph][jh][o] = 0.f;

#pragma unroll 1
  for (int c8 = 0; c8 < 8; ++c8) {
    int ch = csub*8 + c8;
    int cg = s*32 + ch;                 // uniform -> s_load weights
    float xv[2][2][9];
#pragma unroll
    for (int ph = 0; ph < 2; ++ph)
#pragma unroll
      for (int jh = 0; jh < 2; ++jh)
#pragma unroll
        for (int di = 0; di < 3; ++di)
#pragma unroll
          for (int dj = 0; dj < 3; ++dj)
            xv[ph][jh][di*3+dj] =
              smem[ch*340 + (li + ph*4 + di)*34 + (lj + jh*16 + dj)];

#pragma unroll
    for (int o = 0; o < 18; ++o) {
      const float* wr = w_p + (o*C + cg)*9;
#pragma unroll
      for (int n = 0; n < 9; ++n) {
        float wv = wr[n];
        acc[0][0][o] += xv[0][0][n]*wv; acc[0][1][o] += xv[0][1][n]*wv;
        acc[1][0][o] += xv[1][0][n]*wv; acc[1][1][o] += xv[1][1][n]*wv;
      }
    }
#pragma unroll
    for (int o = 0; o < 9; ++o) {
      const float* wr = w_m + (o*C + cg)*9;
#pragma unroll
      for (int n = 0; n < 9; ++n) {
        float wv = wr[n];
        acc[0][0][18+o] += xv[0][0][n]*wv; acc[0][1][18+o] += xv[0][1][n]*wv;
        acc[1][0][18+o] += xv[1][0][n]*wv; acc[1][1][18+o] += xv[1][1][n]*wv;
      }
    }
  }

  // ---- tree reduce across csub; stride 29 (odd) -> no bank conflicts ----
#define RED(cs,phjh,o) smem[((((cs)*4 + (phjh))*64) + pl)*29 + (o)]
  __syncthreads();
  if (csub >= 2) {
#pragma unroll
    for (int ph = 0; ph < 2; ++ph)
#pragma unroll
      for (int jh = 0; jh < 2; ++jh)
#pragma unroll
        for (int o = 0; o < 27; ++o) RED(csub-2, ph*2+jh, o) = acc[ph][jh][o];
  }
  __syncthreads();
  if (csub < 2) {
#pragma unroll
    for (int ph = 0; ph < 2; ++ph)
#pragma unroll
      for (int jh = 0; jh < 2; ++jh)
#pragma unroll
        for (int o = 0; o < 27; ++o) acc[ph][jh][o] += RED(csub, ph*2+jh, o);
  }
  __syncthreads();
  if (csub == 1) {
#pragma unroll
    for (int ph = 0; ph < 2; ++ph)
#pragma unroll
      for (int jh = 0; jh < 2; ++jh)
#pragma unroll
        for (int o = 0; o < 27; ++o) RED(0, ph*2+jh, o) = acc[ph][jh][o];
  }
  __syncthreads();
  if (csub == 0) {
    float* pb = part + ((long)(s*BATCH + b)*27)*NPIX;
#pragma unroll
    for (int ph = 0; ph < 2; ++ph)
#pragma unroll
      for (int jh = 0; jh < 2; ++jh) {
        int p = (i0 + li + ph*4)*W + (j0 + lj + jh*16);
#pragma unroll
        for (int o = 0; o < 27; ++o)
          pb[(long)o*NPIX + p] = acc[ph][jh][o] + RED(0, ph*2+jh, o);
      }
  }
#undef RED
}

// ---------------------------------------------------------------------------
// Kernel 2: pack w_conv into A-frag bf16 layout under K-permutation
// k' = n*128 + c. wPack[kq'][oc][e], k' = kq'*8+e; n = kq'>>4, c = (kq'&15)*8+e.
// ---------------------------------------------------------------------------
__global__ __launch_bounds__(256) void wpack_kernel(
    const float* __restrict__ w_conv, unsigned short* __restrict__ wPack)
{
  int g  = blockIdx.x*256 + threadIdx.x;   // 0..18431
  int oc = g & 127;
  int kq = g >> 7;                          // 0..143
  int n  = kq >> 4;
  int c0 = (kq & 15) * 8;
  const float* src = w_conv + oc*1152 + n;
  float f[8];
#pragma unroll
  for (int e = 0; e < 8; ++e) f[e] = src[(c0+e)*9];
  unsigned p0 = (unsigned)f2bf(f[0]) | ((unsigned)f2bf(f[1])<<16);
  unsigned p1 = (unsigned)f2bf(f[2]) | ((unsigned)f2bf(f[3])<<16);
  unsigned p2 = (unsigned)f2bf(f[4]) | ((unsigned)f2bf(f[5])<<16);
  unsigned p3 = (unsigned)f2bf(f[6]) | ((unsigned)f2bf(f[7])<<16);
  *(uint4*)(wPack + (long)g*8) = make_uint4(p0,p1,p2,p3);
}

// ---------------------------------------------------------------------------
// Kernel 3: fused bilinear sampling + MFMA GEMM, NHWC gathers.
// NEW vs round 7: bijective XCD swizzle (1024 blocks, 1024%8==0) so each XCD
// owns a contiguous 32-row band -> gather working set ~1.1 MB fits its 4 MB L2.
// Everything else identical (proven pipeline).
// ---------------------------------------------------------------------------
__global__ __launch_bounds__(256) void dcn_kernel(
    const float* __restrict__ xT, const float* __restrict__ part,
    const float* __restrict__ b_p, const float* __restrict__ b_m,
    const unsigned short* __restrict__ wPack, float* __restrict__ out)
{
  __shared__ int4   mIv[9*PX];
  __shared__ float4 mWv[9*PX];
  __shared__ unsigned short sP[2][8*PX*8];

  // XCD-aware swizzle: XCD j (= blockIdx%8) gets logical [j*128, (j+1)*128)
  int logical = ((blockIdx.x & 7) << 7) | (blockIdx.x >> 3);
  int b     = logical >> 9;
  int pbase = (logical & 511) * PX;
  int tid   = threadIdx.x;
  int lane  = tid & 63;
  int wid   = tid >> 6;

  // ---- phase 0: sampling metadata ----
  for (int v = tid; v < 9*PX; v += 256) {
    int px = v & (PX-1);
    int n  = v >> 5;
    int p  = pbase + px;
    int i = p >> 7, j = p & 127;

    const float* pp = part + (long)b*27*NPIX + p;
    const long ss = (long)BATCH*27*NPIX;
    float offx = b_p[n], offy = b_p[9+n], mm = b_m[n];
#pragma unroll
    for (int s = 0; s < 4; ++s) {
      offx += pp[s*ss + (long)n*NPIX];
      offy += pp[s*ss + (long)(9+n)*NPIX];
      mm   += pp[s*ss + (long)(18+n)*NPIX];
    }
    float mv = 1.f/(1.f + expf(-mm));

    float px_ = offx + (float)(i+1) + (float)(n/3 - 1);
    float py_ = offy + (float)(j+1) + (float)(n%3 - 1);
    float fx = floorf(px_), fy = floorf(py_);
    int qltx = min(max((int)fx,     0), 129);
    int qlty = min(max((int)fy,     0), 129);
    int qrbx = min(max((int)fx + 1, 0), 129);
    int qrby = min(max((int)fy + 1, 0), 129);
    px_ = fminf(fmaxf(px_, 0.f), 129.f);
    py_ = fminf(fmaxf(py_, 0.f), 129.f);
    float gxl = 1.f + ((float)qltx - px_);
    float gxr = 1.f - ((float)qrbx - px_);
    float gyl = 1.f + ((float)qlty - py_);
    float gyr = 1.f - ((float)qrby - py_);

    int   qx[4] = {qltx, qrbx, qltx, qrbx};
    int   qy[4] = {qlty, qrby, qrby, qlty};
    float gw[4] = {gxl*gyl, gxr*gyr, gxl*gyr, gxr*gyl};
    int   ii[4]; float ww[4];
#pragma unroll
    for (int cn = 0; cn < 4; ++cn) {
      bool valid = (qx[cn]>=1)&&(qx[cn]<=H)&&(qy[cn]>=1)&&(qy[cn]<=W);
      ii[cn] = valid ? ((qx[cn]-1)*W + (qy[cn]-1)) : 0;
      ww[cn] = valid ? gw[cn]*mv : 0.f;
    }
    mIv[v] = make_int4(ii[0], ii[1], ii[2], ii[3]);
    mWv[v] = make_float4(ww[0], ww[1], ww[2], ww[3]);
  }
  __syncthreads();

  f32x4 acc[2][2];
#pragma unroll
  for (int a_ = 0; a_ < 2; ++a_)
#pragma unroll
    for (int b_ = 0; b_ < 2; ++b_) acc[a_][b_] = (f32x4){0.f,0.f,0.f,0.f};

  int spx   = tid & 31;
  int ksl8  = tid >> 5;                // 0..7
  int col   = lane & 15;
  int kslot = lane >> 4;

  const float* xTb = xT + (long)b*NPIX*C;
  float4 gv[8];                        // 4 corners x 2 float4 (8 channels)
  bf16x8 aCur[2][2], aNxt[2][2];

#define ISSUE_G(CC) {                                                     \
  int n_ = (CC) >> 1;                                                     \
  int4 iv = mIv[n_*PX + spx];                                             \
  int coff = ((CC)&1)*64 + ksl8*8;                                        \
  const float* p0 = xTb + (long)iv.x*C + coff;                            \
  const float* p1 = xTb + (long)iv.y*C + coff;                            \
  const float* p2 = xTb + (long)iv.z*C + coff;                            \
  const float* p3 = xTb + (long)iv.w*C + coff;                            \
  gv[0] = *(const float4*)p0; gv[1] = *(const float4*)(p0+4);             \
  gv[2] = *(const float4*)p1; gv[3] = *(const float4*)(p1+4);             \
  gv[4] = *(const float4*)p2; gv[5] = *(const float4*)(p2+4);             \
  gv[6] = *(const float4*)p3; gv[7] = *(const float4*)(p3+4); }

#define GC(cn, j) (((const float*)&gv[(cn)*2 + ((j)>>2)])[(j)&3])

#define COMPUTE_S(CC, BUF) {                                              \
  int n_ = (CC) >> 1;                                                     \
  float4 wv = mWv[n_*PX + spx];                                           \
  unsigned pk[4];                                                         \
  _Pragma("unroll")                                                       \
  for (int jp = 0; jp < 4; ++jp) {                                        \
    float s0 = wv.x*GC(0,jp*2)   + wv.y*GC(1,jp*2)                        \
             + wv.z*GC(2,jp*2)   + wv.w*GC(3,jp*2);                       \
    float s1 = wv.x*GC(0,jp*2+1) + wv.y*GC(1,jp*2+1)                      \
             + wv.z*GC(2,jp*2+1) + wv.w*GC(3,jp*2+1);                     \
    pk[jp] = (unsigned)f2bf(s0) | ((unsigned)f2bf(s1)<<16);               \
  }                                                                       \
  *(uint4*)&sP[BUF][(ksl8*PX + spx)*8] = make_uint4(pk[0],pk[1],pk[2],pk[3]); }

#define ISSUE_A(CC, DST) { _Pragma("unroll")                              \
  for (int st = 0; st < 2; ++st) { _Pragma("unroll")                      \
    for (int o2 = 0; o2 < 2; ++o2) {                                      \
      int kq = (CC)*8 + st*4 + kslot;                                     \
      int oc = wid*32 + o2*16 + col;                                      \
      DST[st][o2] = *(const bf16x8*)(wPack + ((long)kq*128 + oc)*8);      \
    } } }

#define BARRIER {                                                         \
  __builtin_amdgcn_sched_barrier(0);                                      \
  asm volatile("s_waitcnt lgkmcnt(0)" ::: "memory");                      \
  __builtin_amdgcn_sched_barrier(0);                                      \
  __builtin_amdgcn_s_barrier();                                           \
  __builtin_amdgcn_sched_barrier(0); }

#define DO_MFMA(BUF, AFR) { _Pragma("unroll")                             \
  for (int st = 0; st < 2; ++st) {                                        \
    bf16x8 b0 = *(const bf16x8*)&sP[BUF][((st*4+kslot)*PX +      col)*8]; \
    bf16x8 b1 = *(const bf16x8*)&sP[BUF][((st*4+kslot)*PX + 16 + col)*8]; \
    acc[0][0] = __builtin_amdgcn_mfma_f32_16x16x32_bf16(AFR[st][0], b0, acc[0][0], 0,0,0); \
    acc[0][1] = __builtin_amdgcn_mfma_f32_16x16x32_bf16(AFR[st][0], b1, acc[0][1], 0,0,0); \
    acc[1][0] = __builtin_amdgcn_mfma_f32_16x16x32_bf16(AFR[st][1], b0, acc[1][0], 0,0,0); \
    acc[1][1] = __builtin_amdgcn_mfma_f32_16x16x32_bf16(AFR[st][1], b1, acc[1][1], 0,0,0); \
  } }

  ISSUE_G(0)
  ISSUE_A(0, aCur)

  for (int cc2 = 0; cc2 < 9; ++cc2) {
    int ccE = cc2*2, ccO = cc2*2 + 1;

    COMPUTE_S(ccE, 0)                  // waits on gv(ccE)
    ISSUE_G(ccO)                       // in flight across barrier
    BARRIER
    ISSUE_A(ccO, aNxt)
    DO_MFMA(0, aCur)

    COMPUTE_S(ccO, 1)
    if (cc2 < 8) { ISSUE_G(ccE+2) }
    BARRIER
    if (cc2 < 8) { ISSUE_A(ccE+2, aCur) }
    DO_MFMA(1, aNxt)
  }
#undef ISSUE_G
#undef GC
#undef COMPUTE_S
#undef ISSUE_A
#undef BARRIER
#undef DO_MFMA

  // ---- epilogue ----
  int row4 = (lane >> 4) * 4;
#pragma unroll
  for (int o2 = 0; o2 < 2; ++o2)
#pragma unroll
    for (int p2 = 0; p2 < 2; ++p2)
#pragma unroll
      for (int r = 0; r < 4; ++r) {
        int oc = wid*32 + o2*16 + row4 + r;
        int px = pbase + p2*16 + col;
        out[((long)(b*C + oc))*NPIX + px] = acc[o2][p2][r];
      }
}

// ---------------------------------------------------------------------------
extern "C" void kernel_launch(void* const* d_in, const int* in_sizes, int n_in,
                              void* d_out, int out_size, void* d_ws, size_t ws_size,
                              hipStream_t stream) {
  const float* x      = (const float*)d_in[0];
  const float* w_p    = (const float*)d_in[1];
  const float* b_p    = (const float*)d_in[2];
  const float* w_m    = (const float*)d_in[3];
  const float* b_m    = (const float*)d_in[4];
  const float* w_conv = (const float*)d_in[5];
  float* out = (float*)d_out;
  float* part          = (float*)d_ws;
  unsigned short* wPk  = (unsigned short*)((char*)d_ws + WS_WPK_OFF);
  float* xT            = (float*)((char*)d_ws + WS_XT_OFF);   // total 31.2 MB

  conv27_kernel<<<512, 256, 0, stream>>>(x, w_p, w_m, part, xT);
  wpack_kernel<<<72, 256, 0, stream>>>(w_conv, wPk);
  dcn_kernel<<<1024, 256, 0, stream>>>(xT, part, b_p, b_m, wPk, out);
}

// Round 9
// 126.982 us; speedup vs baseline: 1.5783x; 1.5783x over previous
//
#include <hip/hip_runtime.h>
#include <hip/hip_bf16.h>
#include <math.h>

#define H 128
#define W 128
#define C 128
#define BATCH 2
#define NPIX (H*W)            // 16384
#define PX 32                 // pixels per dcn block
#define ZROW (2*NPIX)         // zero row index in xT (padding reads)

// ws layout (bytes): part 3538944 | wPack 294912 | wPack27 73728 | xT 8390656
#define WS_WPK_OFF   3538944
#define WS_WPK27_OFF 3833856
#define WS_XT_OFF    3907584   // total 12,298,240 B

typedef __attribute__((ext_vector_type(8))) short bf16x8;
typedef __attribute__((ext_vector_type(4))) float f32x4;

static __device__ __forceinline__ unsigned short f2bf(float f){
  unsigned u = __float_as_uint(f);
  u += 0x7FFF + ((u >> 16) & 1);          // RNE
  return (unsigned short)(u >> 16);
}

// ---------------------------------------------------------------------------
// Kernel 0: x (NCHW fp32) -> xT (NHWC bf16) + zero row at ZROW.
// Block = 64 px x 128 ch. Reads/writes fully coalesced via LDS tile.
// ---------------------------------------------------------------------------
__global__ __launch_bounds__(256) void xpose_kernel(
    const float* __restrict__ x, unsigned short* __restrict__ xT)
{
  __shared__ float tile[128][65];
  int bidx = blockIdx.x;            // 512 = 2 b x 256 tiles
  int b  = bidx >> 8;
  int p0 = (bidx & 255) << 6;
  int t  = threadIdx.x;

  const float* xb = x + (long)b*C*NPIX;
#pragma unroll
  for (int q = 0; q < 8; ++q) {
    int idx  = q*256 + t;           // 2048 float4 units
    int c    = idx >> 4;
    int quad = idx & 15;
    float4 v = *(const float4*)(xb + (long)c*NPIX + p0 + quad*4);
    tile[c][quad*4+0] = v.x; tile[c][quad*4+1] = v.y;
    tile[c][quad*4+2] = v.z; tile[c][quad*4+3] = v.w;
  }
  __syncthreads();
#pragma unroll
  for (int r = 0; r < 4; ++r) {
    int u = r*256 + t;              // 1024 units: px = u>>4, seg(8ch) = u&15
    int px = u >> 4, seg = u & 15;
    unsigned pk[4];
#pragma unroll
    for (int e2 = 0; e2 < 4; ++e2) {
      float lo = tile[seg*8 + e2*2][px];
      float hi = tile[seg*8 + e2*2 + 1][px];
      pk[e2] = (unsigned)f2bf(lo) | ((unsigned)f2bf(hi) << 16);
    }
    *(uint4*)(xT + ((long)(b*NPIX + p0 + px))*C + seg*8) =
        make_uint4(pk[0],pk[1],pk[2],pk[3]);
  }
  if (bidx == 0 && t < 16)
    *(uint4*)(xT + (long)ZROW*C + t*8) = make_uint4(0,0,0,0);
}

// ---------------------------------------------------------------------------
// Kernel 1: pack w_conv (128oc x 1152k) -> wPack[kq][128oc][8e] bf16,
// K-permutation k' = n*128 + c (as rounds 6-8).
// ---------------------------------------------------------------------------
__global__ __launch_bounds__(256) void wpack_kernel(
    const float* __restrict__ w_conv, unsigned short* __restrict__ wPack)
{
  int g  = blockIdx.x*256 + threadIdx.x;   // 0..18431
  int oc = g & 127;
  int kq = g >> 7;                          // 0..143
  int n  = kq >> 4;
  int c0 = (kq & 15) * 8;
  const float* src = w_conv + oc*1152 + n;
  float f[8];
#pragma unroll
  for (int e = 0; e < 8; ++e) f[e] = src[(c0+e)*9];
  unsigned p0 = (unsigned)f2bf(f[0]) | ((unsigned)f2bf(f[1])<<16);
  unsigned p1 = (unsigned)f2bf(f[2]) | ((unsigned)f2bf(f[3])<<16);
  unsigned p2 = (unsigned)f2bf(f[4]) | ((unsigned)f2bf(f[5])<<16);
  unsigned p3 = (unsigned)f2bf(f[6]) | ((unsigned)f2bf(f[7])<<16);
  *(uint4*)(wPack + (long)g*8) = make_uint4(p0,p1,p2,p3);
}

// ---------------------------------------------------------------------------
// Kernel 2: pack [w_p;w_m;zeros] (32 rows x 1152k) -> wPack27[kq][32][8] bf16,
// same K-permutation. Rows 0-17 = w_p, 18-26 = w_m, 27-31 = 0.
// ---------------------------------------------------------------------------
__global__ __launch_bounds__(256) void wpack27_kernel(
    const float* __restrict__ w_p, const float* __restrict__ w_m,
    unsigned short* __restrict__ wPack27)
{
  int g = blockIdx.x*256 + threadIdx.x;    // 18 blocks -> 4608 exactly
  int oc = g & 31;
  int kq = g >> 5;                          // 0..143
  int n  = kq >> 4;
  int c0 = (kq & 15) * 8;
  unsigned pk[4];
#pragma unroll
  for (int e2 = 0; e2 < 4; ++e2) {
    float f0 = 0.f, f1 = 0.f;
    int ca = c0 + e2*2, cb = ca + 1;
    if (oc < 18)      { f0 = w_p[(oc*C + ca)*9 + n];      f1 = w_p[(oc*C + cb)*9 + n]; }
    else if (oc < 27) { f0 = w_m[((oc-18)*C + ca)*9 + n]; f1 = w_m[((oc-18)*C + cb)*9 + n]; }
    pk[e2] = (unsigned)f2bf(f0) | ((unsigned)f2bf(f1)<<16);
  }
  *(uint4*)(wPack27 + (long)g*8) = make_uint4(pk[0],pk[1],pk[2],pk[3]);
}

// ---------------------------------------------------------------------------
// Kernel 3: 27-channel offset/modulation conv as MFMA GEMM.
// D[32oc x px] = W27[32 x 1152] * xshift[1152 x px]; B-frags loaded DIRECTLY
// from xT at fixed shifted rows (zero row for borders). No LDS staging, no
// barriers; register double-buffer. part[b][27][NPIX] (single copy).
// ---------------------------------------------------------------------------
__global__ __launch_bounds__(256) void off_kernel(
    const unsigned short* __restrict__ xT,
    const unsigned short* __restrict__ wPack27,
    float* __restrict__ part)
{
  __shared__ int mR[9*64];          // shifted row index per (n, px)
  int b     = blockIdx.x >> 8;      // grid 512 = 2 b x 256 tiles of 64 px
  int pbase = (blockIdx.x & 255) << 6;
  int tid = threadIdx.x, lane = tid & 63, wid = tid >> 6;

  for (int v = tid; v < 576; v += 256) {
    int px = v & 63, n = v >> 6;
    int p = pbase + px;
    int i = p >> 7, j = p & 127;
    int ii = i + n/3 - 1, jj = j + n%3 - 1;
    bool valid = ((unsigned)ii < 128u) && ((unsigned)jj < 128u);
    mR[v] = valid ? (b*NPIX + ii*W + jj) : ZROW;
  }
  __syncthreads();

  f32x4 acc[2];
  acc[0] = (f32x4){0.f,0.f,0.f,0.f};
  acc[1] = (f32x4){0.f,0.f,0.f,0.f};
  int col = lane & 15, kslot = lane >> 4;
  int mypx = wid*16 + col;

  bf16x8 aC[2][2], aN[2][2], bC[2], bN[2];

#define OLOADB(CC, DST) { int n_ = (CC) >> 1;                              \
  long row = mR[n_*64 + mypx];                                             \
  const unsigned short* bp = xT + row*C + ((CC)&1)*64 + kslot*8;           \
  DST[0] = *(const bf16x8*)bp; DST[1] = *(const bf16x8*)(bp + 32); }

#define OLOADA(CC, DST) { _Pragma("unroll")                                \
  for (int st = 0; st < 2; ++st) { _Pragma("unroll")                       \
    for (int o2 = 0; o2 < 2; ++o2) {                                       \
      int kq = (CC)*8 + st*4 + kslot;                                      \
      DST[st][o2] = *(const bf16x8*)(wPack27 + ((long)kq*32 + o2*16 + col)*8); } } }

#define OMF(BD, AD) { _Pragma("unroll")                                    \
  for (int st = 0; st < 2; ++st) {                                         \
    acc[0] = __builtin_amdgcn_mfma_f32_16x16x32_bf16(AD[st][0], BD[st], acc[0], 0,0,0); \
    acc[1] = __builtin_amdgcn_mfma_f32_16x16x32_bf16(AD[st][1], BD[st], acc[1], 0,0,0); } }

  OLOADB(0, bC) OLOADA(0, aC)
  for (int c2 = 0; c2 < 9; ++c2) {
    OLOADB(c2*2+1, bN) OLOADA(c2*2+1, aN)
    OMF(bC, aC)
    if (c2 < 8) { OLOADB(c2*2+2, bC) OLOADA(c2*2+2, aC) }
    OMF(bN, aN)
  }
#undef OLOADB
#undef OLOADA
#undef OMF

#pragma unroll
  for (int o2 = 0; o2 < 2; ++o2)
#pragma unroll
    for (int r = 0; r < 4; ++r) {
      int oc = o2*16 + kslot*4 + r;
      if (oc < 27)
        part[((long)b*27 + oc)*NPIX + pbase + mypx] = acc[o2][r];
    }
}

// ---------------------------------------------------------------------------
// Kernel 4: fused bilinear sampling + MFMA GEMM (bf16 xT gathers).
// Producer remap: (spx=tid>>3, ksl8=tid&7) -> 8 lanes share one pixel row,
// each gather instruction reads 8 aligned 128B half-rows (was 32-64 lines).
// 4 x 16B corner loads per chunk per thread (was 8). Pipeline as R4-R8.
// ---------------------------------------------------------------------------
__global__ __launch_bounds__(256) void dcn_kernel(
    const unsigned short* __restrict__ xT, const float* __restrict__ part,
    const float* __restrict__ b_p, const float* __restrict__ b_m,
    const unsigned short* __restrict__ wPack, float* __restrict__ out)
{
  __shared__ int4   mIv[9*PX];
  __shared__ float4 mWv[9*PX];
  __shared__ unsigned short sP[2][8*PX*8];

  int b     = blockIdx.x >> 9;
  int pbase = (blockIdx.x & 511) * PX;
  int tid   = threadIdx.x;
  int lane  = tid & 63;
  int wid   = tid >> 6;

  // ---- phase 0: sampling metadata (part is single-copy now) ----
  for (int v = tid; v < 9*PX; v += 256) {
    int px = v & (PX-1);
    int n  = v >> 5;
    int p  = pbase + px;
    int i = p >> 7, j = p & 127;

    const float* pp = part + (long)b*27*NPIX + p;
    float offx = b_p[n]   + pp[(long)n*NPIX];
    float offy = b_p[9+n] + pp[(long)(9+n)*NPIX];
    float mm   = b_m[n]   + pp[(long)(18+n)*NPIX];
    float mv = 1.f/(1.f + expf(-mm));

    float px_ = offx + (float)(i+1) + (float)(n/3 - 1);
    float py_ = offy + (float)(j+1) + (float)(n%3 - 1);
    float fx = floorf(px_), fy = floorf(py_);
    int qltx = min(max((int)fx,     0), 129);
    int qlty = min(max((int)fy,     0), 129);
    int qrbx = min(max((int)fx + 1, 0), 129);
    int qrby = min(max((int)fy + 1, 0), 129);
    px_ = fminf(fmaxf(px_, 0.f), 129.f);
    py_ = fminf(fmaxf(py_, 0.f), 129.f);
    float gxl = 1.f + ((float)qltx - px_);
    float gxr = 1.f - ((float)qrbx - px_);
    float gyl = 1.f + ((float)qlty - py_);
    float gyr = 1.f - ((float)qrby - py_);

    int   qx[4] = {qltx, qrbx, qltx, qrbx};
    int   qy[4] = {qlty, qrby, qrby, qlty};
    float gw[4] = {gxl*gyl, gxr*gyr, gxl*gyr, gxr*gyl};
    int   ii[4]; float ww[4];
#pragma unroll
    for (int cn = 0; cn < 4; ++cn) {
      bool valid = (qx[cn]>=1)&&(qx[cn]<=H)&&(qy[cn]>=1)&&(qy[cn]<=W);
      ii[cn] = valid ? ((qx[cn]-1)*W + (qy[cn]-1)) : 0;
      ww[cn] = valid ? gw[cn]*mv : 0.f;
    }
    mIv[v] = make_int4(ii[0], ii[1], ii[2], ii[3]);
    mWv[v] = make_float4(ww[0], ww[1], ww[2], ww[3]);
  }
  __syncthreads();

  f32x4 acc[2][2];
#pragma unroll
  for (int a_ = 0; a_ < 2; ++a_)
#pragma unroll
    for (int b_ = 0; b_ < 2; ++b_) acc[a_][b_] = (f32x4){0.f,0.f,0.f,0.f};

  int spx   = tid >> 3;                // producer pixel (8 lanes/row -> coalesced)
  int ksl8  = tid & 7;                 // producer k-slot
  int col   = lane & 15;
  int kslot = lane >> 4;

  const unsigned short* xTb = xT + (long)b*NPIX*C;
  uint4 gv4[4];                        // 4 corners x 8 bf16 channels
  bf16x8 aCur[2][2], aNxt[2][2];

#define ISSUE_G(CC) {                                                     \
  int n_ = (CC) >> 1;                                                     \
  int4 iv = mIv[n_*PX + spx];                                             \
  int coff = ((CC)&1)*64 + ksl8*8;                                        \
  gv4[0] = *(const uint4*)(xTb + (long)iv.x*C + coff);                    \
  gv4[1] = *(const uint4*)(xTb + (long)iv.y*C + coff);                    \
  gv4[2] = *(const uint4*)(xTb + (long)iv.z*C + coff);                    \
  gv4[3] = *(const uint4*)(xTb + (long)iv.w*C + coff); }

#define GCD(cn, j) (((const unsigned*)&gv4[cn])[(j)])
#define CLO(d) __uint_as_float((d)<<16)
#define CHI(d) __uint_as_float((d)&0xFFFF0000u)

#define COMPUTE_S(CC, BUF) {                                              \
  int n_ = (CC) >> 1;                                                     \
  float4 wv = mWv[n_*PX + spx];                                           \
  unsigned pk[4];                                                         \
  _Pragma("unroll")                                                       \
  for (int jp = 0; jp < 4; ++jp) {                                        \
    unsigned d0=GCD(0,jp), d1=GCD(1,jp), d2=GCD(2,jp), d3=GCD(3,jp);      \
    float s0 = wv.x*CLO(d0) + wv.y*CLO(d1) + wv.z*CLO(d2) + wv.w*CLO(d3); \
    float s1 = wv.x*CHI(d0) + wv.y*CHI(d1) + wv.z*CHI(d2) + wv.w*CHI(d3); \
    pk[jp] = (unsigned)f2bf(s0) | ((unsigned)f2bf(s1)<<16);               \
  }                                                                       \
  *(uint4*)&sP[BUF][(ksl8*PX + spx)*8] = make_uint4(pk[0],pk[1],pk[2],pk[3]); }

#define ISSUE_A(CC, DST) { _Pragma("unroll")                              \
  for (int st = 0; st < 2; ++st) { _Pragma("unroll")                      \
    for (int o2 = 0; o2 < 2; ++o2) {                                      \
      int kq = (CC)*8 + st*4 + kslot;                                     \
      int oc = wid*32 + o2*16 + col;                                      \
      DST[st][o2] = *(const bf16x8*)(wPack + ((long)kq*128 + oc)*8);      \
    } } }

#define BARRIER {                                                         \
  __builtin_amdgcn_sched_barrier(0);                                      \
  asm volatile("s_waitcnt lgkmcnt(0)" ::: "memory");                      \
  __builtin_amdgcn_sched_barrier(0);                                      \
  __builtin_amdgcn_s_barrier();                                           \
  __builtin_amdgcn_sched_barrier(0); }

#define DO_MFMA(BUF, AFR) { _Pragma("unroll")                             \
  for (int st = 0; st < 2; ++st) {                                        \
    bf16x8 b0 = *(const bf16x8*)&sP[BUF][((st*4+kslot)*PX +      col)*8]; \
    bf16x8 b1 = *(const bf16x8*)&sP[BUF][((st*4+kslot)*PX + 16 + col)*8]; \
    acc[0][0] = __builtin_amdgcn_mfma_f32_16x16x32_bf16(AFR[st][0], b0, acc[0][0], 0,0,0); \
    acc[0][1] = __builtin_amdgcn_mfma_f32_16x16x32_bf16(AFR[st][0], b1, acc[0][1], 0,0,0); \
    acc[1][0] = __builtin_amdgcn_mfma_f32_16x16x32_bf16(AFR[st][1], b0, acc[1][0], 0,0,0); \
    acc[1][1] = __builtin_amdgcn_mfma_f32_16x16x32_bf16(AFR[st][1], b1, acc[1][1], 0,0,0); \
  } }

  ISSUE_G(0)
  ISSUE_A(0, aCur)

  for (int cc2 = 0; cc2 < 9; ++cc2) {
    int ccE = cc2*2, ccO = cc2*2 + 1;

    COMPUTE_S(ccE, 0)                  // waits on gv4(ccE)
    ISSUE_G(ccO)                       // in flight across barrier
    BARRIER
    ISSUE_A(ccO, aNxt)
    DO_MFMA(0, aCur)

    COMPUTE_S(ccO, 1)
    if (cc2 < 8) { ISSUE_G(ccE+2) }
    BARRIER
    if (cc2 < 8) { ISSUE_A(ccE+2, aCur) }
    DO_MFMA(1, aNxt)
  }
#undef ISSUE_G
#undef GCD
#undef CLO
#undef CHI
#undef COMPUTE_S
#undef ISSUE_A
#undef BARRIER
#undef DO_MFMA

  // ---- epilogue ----
  int row4 = (lane >> 4) * 4;
#pragma unroll
  for (int o2 = 0; o2 < 2; ++o2)
#pragma unroll
    for (int p2 = 0; p2 < 2; ++p2)
#pragma unroll
      for (int r = 0; r < 4; ++r) {
        int oc = wid*32 + o2*16 + row4 + r;
        int px = pbase + p2*16 + col;
        out[((long)(b*C + oc))*NPIX + px] = acc[o2][p2][r];
      }
}

// ---------------------------------------------------------------------------
extern "C" void kernel_launch(void* const* d_in, const int* in_sizes, int n_in,
                              void* d_out, int out_size, void* d_ws, size_t ws_size,
                              hipStream_t stream) {
  const float* x      = (const float*)d_in[0];
  const float* w_p    = (const float*)d_in[1];
  const float* b_p    = (const float*)d_in[2];
  const float* w_m    = (const float*)d_in[3];
  const float* b_m    = (const float*)d_in[4];
  const float* w_conv = (const float*)d_in[5];
  float* out = (float*)d_out;

  float*          part  = (float*)d_ws;
  unsigned short* wPk   = (unsigned short*)((char*)d_ws + WS_WPK_OFF);
  unsigned short* wPk27 = (unsigned short*)((char*)d_ws + WS_WPK27_OFF);
  unsigned short* xT    = (unsigned short*)((char*)d_ws + WS_XT_OFF);

  xpose_kernel <<<512, 256, 0, stream>>>(x, xT);
  wpack_kernel <<<72,  256, 0, stream>>>(w_conv, wPk);
  wpack27_kernel<<<18, 256, 0, stream>>>(w_p, w_m, wPk27);
  off_kernel   <<<512, 256, 0, stream>>>(xT, wPk27, part);
  dcn_kernel   <<<1024,256, 0, stream>>>(xT, part, b_p, b_m, wPk, out);
}